// Round 1
// baseline (361.751 us; speedup 1.0000x reference)
//
#include <hip/hip_runtime.h>
#include <math.h>

// Problem dims
#define BN 4
#define SN 512
#define DN 768
#define NHN 12
#define DHN 64
#define EXPN 32
#define INVN 64

// ---------------------------------------------------------------------------
// Kernel 1: fused QKV projection.
// C[m,n] = sum_k X[m,k] * W[n,k] + b[n], written to [B,NH,S,DH] layout.
// BM=BN=64, BK=16, 256 threads, 4x4 microtile, k-major LDS tiles.
// ---------------------------------------------------------------------------
__global__ __launch_bounds__(256) void qkv_gemm(
    const float* __restrict__ X,
    const float* __restrict__ Wq, const float* __restrict__ bq,
    const float* __restrict__ Wk, const float* __restrict__ bk,
    const float* __restrict__ Wv, const float* __restrict__ bv,
    float* __restrict__ qo, float* __restrict__ ko, float* __restrict__ vo)
{
    const float* W; const float* bias; float* out;
    if (blockIdx.z == 0)      { W = Wq; bias = bq; out = qo; }
    else if (blockIdx.z == 1) { W = Wk; bias = bk; out = ko; }
    else                      { W = Wv; bias = bv; out = vo; }

    __shared__ float As[16][64];   // k-major
    __shared__ float Bs[16][64];

    const int tid = threadIdx.x;
    const int m0 = blockIdx.y * 64;
    const int n0 = blockIdx.x * 64;
    const int lm = tid >> 2;          // 0..63 : row within tile
    const int ks = (tid & 3) * 4;     // 0,4,8,12 : k segment
    const int rb = (tid >> 4) * 4;    // microtile row base
    const int cb = (tid & 15) * 4;    // microtile col base

    float acc[4][4];
    #pragma unroll
    for (int i = 0; i < 4; ++i)
        #pragma unroll
        for (int j = 0; j < 4; ++j) acc[i][j] = 0.f;

    for (int k0 = 0; k0 < DN; k0 += 16) {
        float4 a = *(const float4*)&X[(m0 + lm) * DN + k0 + ks];
        float4 w = *(const float4*)&W[(n0 + lm) * DN + k0 + ks];
        __syncthreads();
        As[ks + 0][lm] = a.x; As[ks + 1][lm] = a.y;
        As[ks + 2][lm] = a.z; As[ks + 3][lm] = a.w;
        Bs[ks + 0][lm] = w.x; Bs[ks + 1][lm] = w.y;
        Bs[ks + 2][lm] = w.z; Bs[ks + 3][lm] = w.w;
        __syncthreads();
        #pragma unroll
        for (int kk = 0; kk < 16; ++kk) {
            float4 av = *(const float4*)&As[kk][rb];
            float4 bv4 = *(const float4*)&Bs[kk][cb];
            float ar[4] = { av.x, av.y, av.z, av.w };
            float br[4] = { bv4.x, bv4.y, bv4.z, bv4.w };
            #pragma unroll
            for (int i = 0; i < 4; ++i)
                #pragma unroll
                for (int j = 0; j < 4; ++j)
                    acc[i][j] += ar[i] * br[j];
        }
    }

    #pragma unroll
    for (int i = 0; i < 4; ++i) {
        int m = m0 + rb + i;
        int b = m >> 9;          // /512
        int s = m & 511;
        #pragma unroll
        for (int j = 0; j < 4; ++j) {
            int n = n0 + cb + j;
            int h = n >> 6;      // /64
            int dh = n & 63;
            out[(((b * NHN + h) * SN) + s) * DHN + dh] = acc[i][j] + bias[n];
        }
    }
}

// ---------------------------------------------------------------------------
// Kernel 2: attention + fit_softmax, one block per (head, 32 query rows).
// ---------------------------------------------------------------------------
__global__ __launch_bounds__(256) void attn_kernel(
    const float* __restrict__ q, const float* __restrict__ k,
    const float* __restrict__ v, const float* __restrict__ mask,
    const float* __restrict__ ew1, const float* __restrict__ eb1,
    const float* __restrict__ ew2, const float* __restrict__ eb2,
    const float* __restrict__ iw1, const float* __restrict__ ib1,
    const float* __restrict__ iw2, const float* __restrict__ ib2,
    float* __restrict__ out)
{
    __shared__ float sc[32][512];      // scores / probs tile (64 KB)
    __shared__ float Qs[32][64];       // Q tile
    __shared__ float Ks[64][65];       // K / V chunk (padded stride 65)
    __shared__ float Q0s[64];          // Q row 0 of this head
    __shared__ float refs[32];         // per-row reference value
    __shared__ float wE1[EXPN], wEb1[EXPN], wE2[EXPN];
    __shared__ float wI1[INVN], wIb1[INVN], wI2[INVN];
    __shared__ float eb2s, ib2s;

    const int tid = threadIdx.x;
    const int bh = blockIdx.y;         // 0..47
    const int b  = bh / NHN;
    const int h  = bh - b * NHN;
    const int q0 = blockIdx.x * 32;

    const float* Qh = q + (size_t)bh * SN * DHN;
    const float* Kh = k + (size_t)bh * SN * DHN;
    const float* Vh = v + (size_t)bh * SN * DHN;
    const float* mb = mask + b * SN;

    if (tid < EXPN) { wE1[tid] = ew1[tid]; wEb1[tid] = eb1[tid]; wE2[tid] = ew2[tid]; }
    if (tid < INVN) { wI1[tid] = iw1[tid]; wIb1[tid] = ib1[tid]; wI2[tid] = iw2[tid]; }
    if (tid == 0) { eb2s = eb2[0]; ib2s = ib2[0]; }
    if (tid < 64) Q0s[tid] = Qh[tid];
    // Q tile 32x64
    for (int i = tid; i < 32 * 16; i += 256) {
        int r = i >> 4, seg = (i & 15) * 4;
        *(float4*)&Qs[r][seg] = *(const float4*)&Qh[(q0 + r) * DHN + seg];
    }
    __syncthreads();

    const int lane = tid & 63;
    const int ty = tid >> 6;

    // ---- phase 1: scores = QK^T/8 + mask ----
    for (int c0 = 0; c0 < SN; c0 += 64) {
        __syncthreads();   // protect Ks reuse
        for (int i = tid; i < 64 * 16; i += 256) {
            int r = i >> 4, seg = (i & 15) * 4;
            float4 kv = *(const float4*)&Kh[(c0 + r) * DHN + seg];
            Ks[r][seg + 0] = kv.x; Ks[r][seg + 1] = kv.y;
            Ks[r][seg + 2] = kv.z; Ks[r][seg + 3] = kv.w;
        }
        __syncthreads();

        const int c = c0 + lane;
        float accs[8];
        #pragma unroll
        for (int i = 0; i < 8; ++i) accs[i] = 0.f;
        #pragma unroll
        for (int d = 0; d < 64; d += 4) {
            float k0r = Ks[lane][d + 0];
            float k1r = Ks[lane][d + 1];
            float k2r = Ks[lane][d + 2];
            float k3r = Ks[lane][d + 3];
            #pragma unroll
            for (int i = 0; i < 8; ++i) {
                float4 qv = *(const float4*)&Qs[ty + 4 * i][d];
                accs[i] += qv.x * k0r + qv.y * k1r + qv.z * k2r + qv.w * k3r;
            }
        }
        float mval = mb[c];
        #pragma unroll
        for (int i = 0; i < 8; ++i)
            sc[ty + 4 * i][c] = accs[i] * 0.125f + mval;

        // reference values: score[b,h,0,q0+r] = dot(Q0, K[q0+r])/8 + mask
        if ((q0 >> 6) == (c0 >> 6) && tid < 32) {
            int off = (q0 & 63) + tid;
            float s = 0.f;
            for (int d = 0; d < 64; ++d) s += Q0s[d] * Ks[off][d];
            refs[tid] = s * 0.125f + mb[q0 + tid];
        }
    }
    __syncthreads();

    // ---- phase 2: fit_softmax, wave w handles rows w*8 .. w*8+7 ----
    const float eb2v = eb2s, ib2v = ib2s;
    for (int rr = 0; rr < 8; ++rr) {
        const int r = ty * 8 + rr;
        const float refm1 = refs[r] - 1.0f;
        float xup[8];
        float part = 0.f;
        #pragma unroll
        for (int j = 0; j < 8; ++j) {
            float x = sc[r][lane + 64 * j];
            float tp = fminf(x - refm1, 3.0f);
            float e = eb2v;
            #pragma unroll
            for (int n = 0; n < EXPN; ++n) {
                float hh = tp * wE1[n] + wEb1[n];
                e += fmaxf(hh, 0.f) * wE2[n];
            }
            e = (tp > -20.0f) ? e : 0.f;
            xup[j] = e;
            part += e;
        }
        #pragma unroll
        for (int s = 32; s > 0; s >>= 1) part += __shfl_xor(part, s);
        // inv MLP #1 (lane-parallel over 64 units)
        float hu = fmaxf(part * wI1[lane] + wIb1[lane], 0.f) * wI2[lane];
        #pragma unroll
        for (int s = 32; s > 0; s >>= 1) hu += __shfl_xor(hu, s);
        const float pinv = hu + ib2v;

        float p2 = 0.f;
        #pragma unroll
        for (int j = 0; j < 8; ++j) { xup[j] *= pinv; p2 += xup[j]; }
        #pragma unroll
        for (int s = 32; s > 0; s >>= 1) p2 += __shfl_xor(p2, s);
        // inv MLP #2
        float hu2 = fmaxf(p2 * wI1[lane] + wIb1[lane], 0.f) * wI2[lane];
        #pragma unroll
        for (int s = 32; s > 0; s >>= 1) hu2 += __shfl_xor(hu2, s);
        const float pinv2 = hu2 + ib2v;
        const float scale = (p2 > 1.5f) ? pinv2 : 1.0f;
        #pragma unroll
        for (int j = 0; j < 8; ++j) sc[r][lane + 64 * j] = xup[j] * scale;
    }
    __syncthreads();

    // ---- phase 3: ctx = probs @ V ----
    float acc[8];
    #pragma unroll
    for (int i = 0; i < 8; ++i) acc[i] = 0.f;
    for (int c0 = 0; c0 < SN; c0 += 64) {
        __syncthreads();
        for (int i = tid; i < 64 * 16; i += 256) {
            int r = i >> 4, seg = (i & 15) * 4;
            float4 vv = *(const float4*)&Vh[(c0 + r) * DHN + seg];
            Ks[r][seg + 0] = vv.x; Ks[r][seg + 1] = vv.y;
            Ks[r][seg + 2] = vv.z; Ks[r][seg + 3] = vv.w;
        }
        __syncthreads();
        #pragma unroll 16
        for (int cc = 0; cc < 64; ++cc) {
            float vv = Ks[cc][lane];
            #pragma unroll
            for (int i = 0; i < 8; ++i)
                acc[i] += sc[ty + 4 * i][c0 + cc] * vv;
        }
    }

    #pragma unroll
    for (int i = 0; i < 8; ++i) {
        int r = ty + 4 * i;
        out[((size_t)(b * SN + q0 + r)) * DN + h * DHN + lane] = acc[i];
    }
}

// ---------------------------------------------------------------------------
extern "C" void kernel_launch(void* const* d_in, const int* in_sizes, int n_in,
                              void* d_out, int out_size, void* d_ws, size_t ws_size,
                              hipStream_t stream) {
    const float* X    = (const float*)d_in[0];
    const float* mask = (const float*)d_in[1];
    const float* Wq   = (const float*)d_in[2];
    const float* bq   = (const float*)d_in[3];
    const float* Wk   = (const float*)d_in[4];
    const float* bk   = (const float*)d_in[5];
    const float* Wv   = (const float*)d_in[6];
    const float* bv   = (const float*)d_in[7];
    const float* ew1  = (const float*)d_in[8];
    const float* eb1  = (const float*)d_in[9];
    const float* ew2  = (const float*)d_in[10];
    const float* eb2  = (const float*)d_in[11];
    const float* iw1  = (const float*)d_in[12];
    const float* ib1  = (const float*)d_in[13];
    const float* iw2  = (const float*)d_in[14];
    const float* ib2  = (const float*)d_in[15];
    float* out = (float*)d_out;

    const size_t per = (size_t)BN * NHN * SN * DHN;  // 1,572,864 floats
    float* qb = (float*)d_ws;
    float* kb = qb + per;
    float* vb = kb + per;

    dim3 g1(DN / 64, (BN * SN) / 64, 3);   // (12, 32, 3)
    qkv_gemm<<<g1, 256, 0, stream>>>(X, Wq, bq, Wk, bk, Wv, bv, qb, kb, vb);

    dim3 g2(SN / 32, BN * NHN);            // (16, 48)
    attn_kernel<<<g2, 256, 0, stream>>>(qb, kb, vb, mask,
                                        ew1, eb1, ew2, eb2,
                                        iw1, ib1, iw2, ib2, out);
}

// Round 2
// 132.952 us; speedup vs baseline: 2.7209x; 2.7209x over previous
//
#include <hip/hip_runtime.h>
#include <math.h>

typedef unsigned short u16;
typedef short bf16x8 __attribute__((ext_vector_type(8)));
typedef float f32x4 __attribute__((ext_vector_type(4)));

#define BN 4
#define SN 512
#define DN 768
#define NHN 12
#define DHN 64
#define EXPN 32
#define INVN 64

__device__ __forceinline__ u16 f2b(float f) {
    union { float f; unsigned int u; } v; v.f = f;
    unsigned int r = v.u + 0x7FFFu + ((v.u >> 16) & 1u);
    return (u16)(r >> 16);
}
__device__ __forceinline__ float b2f(u16 h) {
    union { unsigned int u; float f; } v; v.u = ((unsigned int)h) << 16;
    return v.f;
}

// ---------------------------------------------------------------------------
// Kernel 0: f32 -> bf16 conversion of X and the three weight matrices.
// ---------------------------------------------------------------------------
__global__ __launch_bounds__(256) void cvt_bf16(
    const float* __restrict__ X, const float* __restrict__ Wq,
    const float* __restrict__ Wk, const float* __restrict__ Wv,
    u16* __restrict__ Xb, u16* __restrict__ Wqb,
    u16* __restrict__ Wkb, u16* __restrict__ Wvb)
{
    const float* s; u16* d; int n;
    switch (blockIdx.y) {
        case 0:  s = X;  d = Xb;  n = (BN * SN) * DN; break;
        case 1:  s = Wq; d = Wqb; n = DN * DN; break;
        case 2:  s = Wk; d = Wkb; n = DN * DN; break;
        default: s = Wv; d = Wvb; n = DN * DN; break;
    }
    int i = (blockIdx.x * 256 + threadIdx.x) * 4;
    if (i < n) {
        float4 v = *(const float4*)&s[i];
        unsigned int lo = (unsigned)f2b(v.x) | ((unsigned)f2b(v.y) << 16);
        unsigned int hi = (unsigned)f2b(v.z) | ((unsigned)f2b(v.w) << 16);
        *(uint2*)&d[i] = make_uint2(lo, hi);
    }
}

// ---------------------------------------------------------------------------
// Kernel 1: QKV projection, bf16 MFMA, direct-global fragment loads.
// C[m,n] = sum_k X[m,k]*W[n,k] + b[n] -> bf16 [B,NH,S,DH].
// Block: 64x64 tile, 4 waves (one 16-row m-tile each), K=768 in steps of 32.
// ---------------------------------------------------------------------------
__global__ __launch_bounds__(256) void qkv_mfma(
    const u16* __restrict__ Xb,
    const u16* __restrict__ Wqb, const u16* __restrict__ Wkb, const u16* __restrict__ Wvb,
    const float* __restrict__ bq, const float* __restrict__ bk, const float* __restrict__ bv,
    u16* __restrict__ Qb, u16* __restrict__ Kb, u16* __restrict__ Vb)
{
    const u16* W; const float* bias; u16* out;
    if (blockIdx.z == 0)      { W = Wqb; bias = bq; out = Qb; }
    else if (blockIdx.z == 1) { W = Wkb; bias = bk; out = Kb; }
    else                      { W = Wvb; bias = bv; out = Vb; }

    const int tid = threadIdx.x, w = tid >> 6, l = tid & 63;
    const int lr = l & 15, lg = l >> 4, kb8 = lg * 8;
    const int m0 = blockIdx.y * 64, n0 = blockIdx.x * 64;

    f32x4 acc[4];
    #pragma unroll
    for (int nt = 0; nt < 4; ++nt) acc[nt] = (f32x4){0.f, 0.f, 0.f, 0.f};

    const u16* ap = Xb + (m0 + w * 16 + lr) * DN + kb8;
    #pragma unroll 4
    for (int k0 = 0; k0 < DN; k0 += 32) {
        bf16x8 a = *(const bf16x8*)(ap + k0);
        #pragma unroll
        for (int nt = 0; nt < 4; ++nt) {
            bf16x8 bb = *(const bf16x8*)(W + (n0 + nt * 16 + lr) * DN + kb8 + k0);
            acc[nt] = __builtin_amdgcn_mfma_f32_16x16x32_bf16(a, bb, acc[nt], 0, 0, 0);
        }
    }

    const int rowb = m0 + w * 16 + lg * 4;
    #pragma unroll
    for (int nt = 0; nt < 4; ++nt) {
        int col = n0 + nt * 16 + lr;
        float bcol = bias[col];
        int hh = col >> 6, dh = col & 63;
        #pragma unroll
        for (int r = 0; r < 4; ++r) {
            int m = rowb + r;
            int bi = m >> 9, srow = m & 511;
            out[(((bi * NHN + hh) * SN) + srow) * DHN + dh] = f2b(acc[nt][r] + bcol);
        }
    }
}

// ---------------------------------------------------------------------------
// Kernel 2: attention. MFMA QK^T -> bf16 scores in LDS -> VALU fit_softmax
// -> bf16 probs -> MFMA PV. One block per (head, 32 query rows), 256 thr.
// LDS ~46 KB -> 3 blocks/CU.
// ---------------------------------------------------------------------------
__global__ __launch_bounds__(256) void attn_mfma(
    const u16* __restrict__ Qb, const u16* __restrict__ Kb, const u16* __restrict__ Vb,
    const float* __restrict__ mask,
    const float* __restrict__ ew1, const float* __restrict__ eb1,
    const float* __restrict__ ew2, const float* __restrict__ eb2,
    const float* __restrict__ iw1, const float* __restrict__ ib1,
    const float* __restrict__ iw2, const float* __restrict__ ib2,
    float* __restrict__ out)
{
    __shared__ __align__(16) u16 sb[32][528];   // scores/probs bf16
    __shared__ __align__(16) u16 Vt[64][72];    // V^T chunk (dh-major)
    __shared__ float ms[SN];
    __shared__ float wE1[EXPN], wEb1[EXPN], wE2[EXPN];
    __shared__ float wI1[INVN], wIb1[INVN], wI2[INVN];
    __shared__ float refs[32];
    __shared__ float scal[2];

    const int tid = threadIdx.x, w = tid >> 6, l = tid & 63;
    const int lr = l & 15, lg = l >> 4, kb8 = lg * 8;
    const int bh = blockIdx.y, b = bh / NHN, h = bh % NHN;
    const int q0 = blockIdx.x * 32;
    const u16* Qh = Qb + (size_t)bh * SN * DHN;
    const u16* Kh = Kb + (size_t)bh * SN * DHN;
    const u16* Vh = Vb + (size_t)bh * SN * DHN;

    if (tid < EXPN) { wE1[tid] = ew1[tid]; wEb1[tid] = eb1[tid]; wE2[tid] = ew2[tid]; }
    else if (tid >= 64 && tid < 64 + INVN) {
        int t = tid - 64; wI1[t] = iw1[t]; wIb1[t] = ib1[t]; wI2[t] = iw2[t];
    }
    if (tid == 255) { scal[0] = eb2[0]; scal[1] = ib2[0]; }
    for (int i = tid; i < SN; i += 256) ms[i] = mask[b * SN + i];
    __syncthreads();

    // ---- phase 1: scores = QK^T/8 + mask (MFMA) ----
    const int mt = w & 1, nh2 = w >> 1;
    const int arow = q0 + mt * 16 + lr;
    bf16x8 aq0 = *(const bf16x8*)(Qh + arow * DHN + kb8);
    bf16x8 aq1 = *(const bf16x8*)(Qh + arow * DHN + 32 + kb8);
    #pragma unroll 2
    for (int i = 0; i < 16; ++i) {
        int col0 = (nh2 * 16 + i) * 16;
        const u16* kp = Kh + (col0 + lr) * DHN + kb8;
        bf16x8 b0 = *(const bf16x8*)(kp);
        bf16x8 b1 = *(const bf16x8*)(kp + 32);
        f32x4 d = {0.f, 0.f, 0.f, 0.f};
        d = __builtin_amdgcn_mfma_f32_16x16x32_bf16(aq0, b0, d, 0, 0, 0);
        d = __builtin_amdgcn_mfma_f32_16x16x32_bf16(aq1, b1, d, 0, 0, 0);
        float mv = ms[col0 + lr];
        int rb = mt * 16 + lg * 4;
        #pragma unroll
        for (int r = 0; r < 4; ++r)
            sb[rb + r][col0 + lr] = f2b(d[r] * 0.125f + mv);
    }
    // refs[r] = dot(Q0, K[q0+r])/8 + mask  via Q0-replicated A fragment
    if (w == 0) {
        bf16x8 a00 = *(const bf16x8*)(Qh + kb8);
        bf16x8 a01 = *(const bf16x8*)(Qh + 32 + kb8);
        #pragma unroll
        for (int t = 0; t < 2; ++t) {
            int col0 = q0 + t * 16;
            const u16* kp = Kh + (col0 + lr) * DHN + kb8;
            bf16x8 b0 = *(const bf16x8*)(kp);
            bf16x8 b1 = *(const bf16x8*)(kp + 32);
            f32x4 d = {0.f, 0.f, 0.f, 0.f};
            d = __builtin_amdgcn_mfma_f32_16x16x32_bf16(a00, b0, d, 0, 0, 0);
            d = __builtin_amdgcn_mfma_f32_16x16x32_bf16(a01, b1, d, 0, 0, 0);
            if (lg == 0) refs[t * 16 + lr] = d[0] * 0.125f + ms[col0 + lr];
        }
    }
    __syncthreads();

    // ---- phase 2: fit_softmax (VALU), wave w owns rows w*8..w*8+7 ----
    const float eb2v = scal[0], ib2v = scal[1];
    for (int rr = 0; rr < 8; ++rr) {
        const int r = w * 8 + rr;
        const float refm1 = refs[r] - 1.0f;
        float tp[8], e[8];
        #pragma unroll
        for (int j = 0; j < 8; ++j) {
            float x = b2f(sb[r][l + 64 * j]);
            tp[j] = fminf(x - refm1, 3.0f);
            e[j] = eb2v;
        }
        #pragma unroll 4
        for (int n = 0; n < EXPN; ++n) {
            float w1 = wE1[n], bb1 = wEb1[n], w2 = wE2[n];
            #pragma unroll
            for (int j = 0; j < 8; ++j)
                e[j] += fmaxf(tp[j] * w1 + bb1, 0.f) * w2;
        }
        float xup[8];
        float part = 0.f;
        #pragma unroll
        for (int j = 0; j < 8; ++j) {
            xup[j] = (tp[j] > -20.0f) ? e[j] : 0.f;
            part += xup[j];
        }
        #pragma unroll
        for (int s = 32; s > 0; s >>= 1) part += __shfl_xor(part, s);
        float hu = fmaxf(part * wI1[l] + wIb1[l], 0.f) * wI2[l];
        #pragma unroll
        for (int s = 32; s > 0; s >>= 1) hu += __shfl_xor(hu, s);
        const float pinv = hu + ib2v;
        float p2 = 0.f;
        #pragma unroll
        for (int j = 0; j < 8; ++j) { xup[j] *= pinv; p2 += xup[j]; }
        #pragma unroll
        for (int s = 32; s > 0; s >>= 1) p2 += __shfl_xor(p2, s);
        float hu2 = fmaxf(p2 * wI1[l] + wIb1[l], 0.f) * wI2[l];
        #pragma unroll
        for (int s = 32; s > 0; s >>= 1) hu2 += __shfl_xor(hu2, s);
        const float pinv2 = hu2 + ib2v;
        const float scale = (p2 > 1.5f) ? pinv2 : 1.0f;
        #pragma unroll
        for (int j = 0; j < 8; ++j)
            sb[r][l + 64 * j] = f2b(xup[j] * scale);
    }
    __syncthreads();

    // ---- phase 3: ctx = probs @ V (MFMA), V^T staged per 64-key chunk ----
    f32x4 acc0 = {0.f, 0.f, 0.f, 0.f}, acc1 = {0.f, 0.f, 0.f, 0.f};
    const int ntp = (w >> 1) * 2;
    for (int c0 = 0; c0 < SN; c0 += 64) {
        __syncthreads();
        #pragma unroll
        for (int it = 0; it < 2; ++it) {
            int idx = tid + it * 256;
            int kk = idx & 63, dg = idx >> 6;
            bf16x8 vv = *(const bf16x8*)(Vh + (c0 + kk) * DHN + dg * 8);
            #pragma unroll
            for (int j = 0; j < 8; ++j)
                Vt[dg * 8 + j][kk] = (u16)vv[j];
        }
        __syncthreads();
        #pragma unroll
        for (int ks = 0; ks < 2; ++ks) {
            bf16x8 a  = *(const bf16x8*)(&sb[mt * 16 + lr][c0 + ks * 32 + kb8]);
            bf16x8 b0 = *(const bf16x8*)(&Vt[ntp * 16 + lr][ks * 32 + kb8]);
            bf16x8 b1 = *(const bf16x8*)(&Vt[(ntp + 1) * 16 + lr][ks * 32 + kb8]);
            acc0 = __builtin_amdgcn_mfma_f32_16x16x32_bf16(a, b0, acc0, 0, 0, 0);
            acc1 = __builtin_amdgcn_mfma_f32_16x16x32_bf16(a, b1, acc1, 0, 0, 0);
        }
    }
    const int srow = q0 + mt * 16 + lg * 4;
    #pragma unroll
    for (int r = 0; r < 4; ++r) {
        float* op = out + (size_t)(b * SN + srow + r) * DN + h * DHN;
        op[ntp * 16 + lr]       = acc0[r];
        op[(ntp + 1) * 16 + lr] = acc1[r];
    }
}

// ---------------------------------------------------------------------------
extern "C" void kernel_launch(void* const* d_in, const int* in_sizes, int n_in,
                              void* d_out, int out_size, void* d_ws, size_t ws_size,
                              hipStream_t stream) {
    const float* X    = (const float*)d_in[0];
    const float* mask = (const float*)d_in[1];
    const float* Wq   = (const float*)d_in[2];
    const float* bq   = (const float*)d_in[3];
    const float* Wk   = (const float*)d_in[4];
    const float* bk   = (const float*)d_in[5];
    const float* Wv   = (const float*)d_in[6];
    const float* bv   = (const float*)d_in[7];
    const float* ew1  = (const float*)d_in[8];
    const float* eb1  = (const float*)d_in[9];
    const float* ew2  = (const float*)d_in[10];
    const float* eb2  = (const float*)d_in[11];
    const float* iw1  = (const float*)d_in[12];
    const float* ib1  = (const float*)d_in[13];
    const float* iw2  = (const float*)d_in[14];
    const float* ib2  = (const float*)d_in[15];
    float* out = (float*)d_out;

    u16* Xb  = (u16*)d_ws;
    u16* Wqb = Xb + (size_t)(BN * SN) * DN;      // 1,572,864
    u16* Wkb = Wqb + DN * DN;                    // +589,824
    u16* Wvb = Wkb + DN * DN;
    u16* Qb  = Wvb + DN * DN;
    const size_t per = (size_t)BN * NHN * SN * DHN;  // 1,572,864
    u16* Kb2 = Qb + per;
    u16* Vb2 = Kb2 + per;

    dim3 gc(1536, 4);
    cvt_bf16<<<gc, 256, 0, stream>>>(X, Wq, Wk, Wv, Xb, Wqb, Wkb, Wvb);

    dim3 g1(DN / 64, (BN * SN) / 64, 3);   // (12, 32, 3)
    qkv_mfma<<<g1, 256, 0, stream>>>(Xb, Wqb, Wkb, Wvb, bq, bk, bv, Qb, Kb2, Vb2);

    dim3 g2(SN / 32, BN * NHN);            // (16, 48)
    attn_mfma<<<g2, 256, 0, stream>>>(Qb, Kb2, Vb2, mask,
                                      ew1, eb1, ew2, eb2,
                                      iw1, ib1, iw2, ib2, out);
}

// Round 3
// 82.156 us; speedup vs baseline: 4.4032x; 1.6183x over previous
//
#include <hip/hip_runtime.h>
#include <math.h>

typedef unsigned short u16;
typedef short bf16x8 __attribute__((ext_vector_type(8)));
typedef float f32x4 __attribute__((ext_vector_type(4)));

#define BN 4
#define SN 512
#define DN 768
#define NHN 12
#define DHN 64
#define EXPN 32
#define INVN 64

__device__ __forceinline__ u16 f2b(float f) {
    union { float f; unsigned int u; } v; v.f = f;
    unsigned int r = v.u + 0x7FFFu + ((v.u >> 16) & 1u);
    return (u16)(r >> 16);
}
__device__ __forceinline__ float b2f(u16 h) {
    union { unsigned int u; float f; } v; v.u = ((unsigned int)h) << 16;
    return v.f;
}

#define GLD16(g, l) __builtin_amdgcn_global_load_lds( \
    (__attribute__((address_space(1))) const void*)(g), \
    (__attribute__((address_space(3))) void*)(l), 16, 0, 0)

// ---------------------------------------------------------------------------
// Kernel 0: f32 -> bf16 conversion of X and the three weight matrices.
// ---------------------------------------------------------------------------
__global__ __launch_bounds__(256) void cvt_bf16(
    const float* __restrict__ X, const float* __restrict__ Wq,
    const float* __restrict__ Wk, const float* __restrict__ Wv,
    u16* __restrict__ Xb, u16* __restrict__ Wqb,
    u16* __restrict__ Wkb, u16* __restrict__ Wvb)
{
    const float* s; u16* d; int n;
    switch (blockIdx.y) {
        case 0:  s = X;  d = Xb;  n = (BN * SN) * DN; break;
        case 1:  s = Wq; d = Wqb; n = DN * DN; break;
        case 2:  s = Wk; d = Wkb; n = DN * DN; break;
        default: s = Wv; d = Wvb; n = DN * DN; break;
    }
    int i = (blockIdx.x * 256 + threadIdx.x) * 4;
    if (i < n) {
        float4 v = *(const float4*)&s[i];
        unsigned int lo = (unsigned)f2b(v.x) | ((unsigned)f2b(v.y) << 16);
        unsigned int hi = (unsigned)f2b(v.z) | ((unsigned)f2b(v.w) << 16);
        *(uint2*)&d[i] = make_uint2(lo, hi);
    }
}

// ---------------------------------------------------------------------------
// Kernel 1: fused QKV projection, m97-style MFMA GEMM.
// Tile BM=128 x BN=64, BK=32, 4 waves (each 64x32), global_load_lds staging
// with XOR-swizzled LDS (pre-swizzled global source, swizzled ds_read).
// Grid: (36 n-tiles, 16 m-tiles); n-tile / 12 selects Q/K/V.
// ---------------------------------------------------------------------------
__global__ __launch_bounds__(256) void qkv_mfma(
    const u16* __restrict__ Xb,
    const u16* __restrict__ Wqb, const u16* __restrict__ Wkb, const u16* __restrict__ Wvb,
    const float* __restrict__ bq, const float* __restrict__ bk, const float* __restrict__ bv,
    u16* __restrict__ Qb, u16* __restrict__ Kb, u16* __restrict__ Vb)
{
    __shared__ __align__(16) u16 As[128 * 32];   // 8 KB, row stride 64 B
    __shared__ __align__(16) u16 Bs[64 * 32];    // 4 KB

    const int tid = threadIdx.x, w = tid >> 6, l = tid & 63;
    const int lr = l & 15, lg = l >> 4;
    const int m0 = blockIdx.y * 128;
    const int nsel = blockIdx.x / 12;            // 0/1/2 -> Q/K/V
    const int n0l = (blockIdx.x % 12) * 64;      // col within the 768-wide matrix
    const u16* W = (nsel == 0) ? Wqb : (nsel == 1) ? Wkb : Wvb;
    const float* bias = (nsel == 0) ? bq : (nsel == 1) ? bk : bv;
    u16* out = (nsel == 0) ? Qb : (nsel == 1) ? Kb : Vb;

    const int wm = w >> 1, wn = w & 1;           // wave: 64(m) x 32(n) sub-tile

    // staging geometry (linear LDS offset o = issue_base + tid*16):
    //   row = o>>6, slot = (o>>4)&3, swizzled source col = (slot ^ ((row>>1)&3))*8
    const int oA0 = tid * 16;
    const int rA0 = oA0 >> 6, sA0 = (oA0 >> 4) & 3;
    const int cA0 = (sA0 ^ ((rA0 >> 1) & 3)) * 8;
    const int oA1 = oA0 + 4096;
    const int rA1 = oA1 >> 6, sA1 = (oA1 >> 4) & 3;
    const int cA1 = (sA1 ^ ((rA1 >> 1) & 3)) * 8;
    // B uses the same mapping as issue 0
    const u16* gA0 = Xb + (m0 + rA0) * DN + cA0;
    const u16* gA1 = Xb + (m0 + rA1) * DN + cA1;
    const u16* gB  = W + (n0l + rA0) * DN + cA0;

    // swizzled ds_read byte offsets for this lane's fragments
    int offA[4], offB[2];
    #pragma unroll
    for (int mi = 0; mi < 4; ++mi) {
        int row = wm * 64 + mi * 16 + lr;
        offA[mi] = row * 64 + ((lg ^ ((row >> 1) & 3)) * 16);
    }
    #pragma unroll
    for (int ni = 0; ni < 2; ++ni) {
        int row = wn * 32 + ni * 16 + lr;
        offB[ni] = row * 64 + ((lg ^ ((row >> 1) & 3)) * 16);
    }

    f32x4 acc[4][2];
    #pragma unroll
    for (int mi = 0; mi < 4; ++mi)
        #pragma unroll
        for (int ni = 0; ni < 2; ++ni) acc[mi][ni] = (f32x4){0.f, 0.f, 0.f, 0.f};

    for (int k0 = 0; k0 < DN; k0 += 32) {
        __syncthreads();
        GLD16(gA0 + k0, (char*)As + oA0);
        GLD16(gA1 + k0, (char*)As + oA1);
        GLD16(gB  + k0, (char*)Bs + oA0);
        __syncthreads();

        bf16x8 af[4], bff[2];
        #pragma unroll
        for (int mi = 0; mi < 4; ++mi) af[mi] = *(const bf16x8*)((const char*)As + offA[mi]);
        #pragma unroll
        for (int ni = 0; ni < 2; ++ni) bff[ni] = *(const bf16x8*)((const char*)Bs + offB[ni]);
        #pragma unroll
        for (int mi = 0; mi < 4; ++mi)
            #pragma unroll
            for (int ni = 0; ni < 2; ++ni)
                acc[mi][ni] = __builtin_amdgcn_mfma_f32_16x16x32_bf16(af[mi], bff[ni], acc[mi][ni], 0, 0, 0);
    }

    // epilogue: bias + bf16 store to [B,NH,S,DH]
    #pragma unroll
    for (int ni = 0; ni < 2; ++ni) {
        int col = n0l + wn * 32 + ni * 16 + lr;
        float bc = bias[col];
        int hh = col >> 6, dh = col & 63;
        #pragma unroll
        for (int mi = 0; mi < 4; ++mi) {
            #pragma unroll
            for (int r = 0; r < 4; ++r) {
                int m = m0 + wm * 64 + mi * 16 + lg * 4 + r;
                int bi = m >> 9, srow = m & 511;
                out[(((bi * NHN + hh) * SN) + srow) * DHN + dh] = f2b(acc[mi][ni][r] + bc);
            }
        }
    }
}

// ---------------------------------------------------------------------------
// Kernel 2: attention (unchanged from R2). MFMA QK^T -> bf16 scores in LDS ->
// VALU fit_softmax -> bf16 probs -> MFMA PV.
// ---------------------------------------------------------------------------
__global__ __launch_bounds__(256) void attn_mfma(
    const u16* __restrict__ Qb, const u16* __restrict__ Kb, const u16* __restrict__ Vb,
    const float* __restrict__ mask,
    const float* __restrict__ ew1, const float* __restrict__ eb1,
    const float* __restrict__ ew2, const float* __restrict__ eb2,
    const float* __restrict__ iw1, const float* __restrict__ ib1,
    const float* __restrict__ iw2, const float* __restrict__ ib2,
    float* __restrict__ out)
{
    __shared__ __align__(16) u16 sb[32][528];
    __shared__ __align__(16) u16 Vt[64][72];
    __shared__ float ms[SN];
    __shared__ float wE1[EXPN], wEb1[EXPN], wE2[EXPN];
    __shared__ float wI1[INVN], wIb1[INVN], wI2[INVN];
    __shared__ float refs[32];
    __shared__ float scal[2];

    const int tid = threadIdx.x, w = tid >> 6, l = tid & 63;
    const int lr = l & 15, lg = l >> 4, kb8 = lg * 8;
    const int bh = blockIdx.y, b = bh / NHN, h = bh % NHN;
    const int q0 = blockIdx.x * 32;
    const u16* Qh = Qb + (size_t)bh * SN * DHN;
    const u16* Kh = Kb + (size_t)bh * SN * DHN;
    const u16* Vh = Vb + (size_t)bh * SN * DHN;

    if (tid < EXPN) { wE1[tid] = ew1[tid]; wEb1[tid] = eb1[tid]; wE2[tid] = ew2[tid]; }
    else if (tid >= 64 && tid < 64 + INVN) {
        int t = tid - 64; wI1[t] = iw1[t]; wIb1[t] = ib1[t]; wI2[t] = iw2[t];
    }
    if (tid == 255) { scal[0] = eb2[0]; scal[1] = ib2[0]; }
    for (int i = tid; i < SN; i += 256) ms[i] = mask[b * SN + i];
    __syncthreads();

    const int mt = w & 1, nh2 = w >> 1;
    const int arow = q0 + mt * 16 + lr;
    bf16x8 aq0 = *(const bf16x8*)(Qh + arow * DHN + kb8);
    bf16x8 aq1 = *(const bf16x8*)(Qh + arow * DHN + 32 + kb8);
    #pragma unroll 2
    for (int i = 0; i < 16; ++i) {
        int col0 = (nh2 * 16 + i) * 16;
        const u16* kp = Kh + (col0 + lr) * DHN + kb8;
        bf16x8 b0 = *(const bf16x8*)(kp);
        bf16x8 b1 = *(const bf16x8*)(kp + 32);
        f32x4 d = {0.f, 0.f, 0.f, 0.f};
        d = __builtin_amdgcn_mfma_f32_16x16x32_bf16(aq0, b0, d, 0, 0, 0);
        d = __builtin_amdgcn_mfma_f32_16x16x32_bf16(aq1, b1, d, 0, 0, 0);
        float mv = ms[col0 + lr];
        int rb = mt * 16 + lg * 4;
        #pragma unroll
        for (int r = 0; r < 4; ++r)
            sb[rb + r][col0 + lr] = f2b(d[r] * 0.125f + mv);
    }
    if (w == 0) {
        bf16x8 a00 = *(const bf16x8*)(Qh + kb8);
        bf16x8 a01 = *(const bf16x8*)(Qh + 32 + kb8);
        #pragma unroll
        for (int t = 0; t < 2; ++t) {
            int col0 = q0 + t * 16;
            const u16* kp = Kh + (col0 + lr) * DHN + kb8;
            bf16x8 b0 = *(const bf16x8*)(kp);
            bf16x8 b1 = *(const bf16x8*)(kp + 32);
            f32x4 d = {0.f, 0.f, 0.f, 0.f};
            d = __builtin_amdgcn_mfma_f32_16x16x32_bf16(a00, b0, d, 0, 0, 0);
            d = __builtin_amdgcn_mfma_f32_16x16x32_bf16(a01, b1, d, 0, 0, 0);
            if (lg == 0) refs[t * 16 + lr] = d[0] * 0.125f + ms[col0 + lr];
        }
    }
    __syncthreads();

    const float eb2v = scal[0], ib2v = scal[1];
    for (int rr = 0; rr < 8; ++rr) {
        const int r = w * 8 + rr;
        const float refm1 = refs[r] - 1.0f;
        float tp[8], e[8];
        #pragma unroll
        for (int j = 0; j < 8; ++j) {
            float x = b2f(sb[r][l + 64 * j]);
            tp[j] = fminf(x - refm1, 3.0f);
            e[j] = eb2v;
        }
        #pragma unroll 4
        for (int n = 0; n < EXPN; ++n) {
            float w1 = wE1[n], bb1 = wEb1[n], w2 = wE2[n];
            #pragma unroll
            for (int j = 0; j < 8; ++j)
                e[j] += fmaxf(tp[j] * w1 + bb1, 0.f) * w2;
        }
        float xup[8];
        float part = 0.f;
        #pragma unroll
        for (int j = 0; j < 8; ++j) {
            xup[j] = (tp[j] > -20.0f) ? e[j] : 0.f;
            part += xup[j];
        }
        #pragma unroll
        for (int s = 32; s > 0; s >>= 1) part += __shfl_xor(part, s);
        float hu = fmaxf(part * wI1[l] + wIb1[l], 0.f) * wI2[l];
        #pragma unroll
        for (int s = 32; s > 0; s >>= 1) hu += __shfl_xor(hu, s);
        const float pinv = hu + ib2v;
        float p2 = 0.f;
        #pragma unroll
        for (int j = 0; j < 8; ++j) { xup[j] *= pinv; p2 += xup[j]; }
        #pragma unroll
        for (int s = 32; s > 0; s >>= 1) p2 += __shfl_xor(p2, s);
        float hu2 = fmaxf(p2 * wI1[l] + wIb1[l], 0.f) * wI2[l];
        #pragma unroll
        for (int s = 32; s > 0; s >>= 1) hu2 += __shfl_xor(hu2, s);
        const float pinv2 = hu2 + ib2v;
        const float scale = (p2 > 1.5f) ? pinv2 : 1.0f;
        #pragma unroll
        for (int j = 0; j < 8; ++j)
            sb[r][l + 64 * j] = f2b(xup[j] * scale);
    }
    __syncthreads();

    f32x4 acc0 = {0.f, 0.f, 0.f, 0.f}, acc1 = {0.f, 0.f, 0.f, 0.f};
    const int ntp = (w >> 1) * 2;
    for (int c0 = 0; c0 < SN; c0 += 64) {
        __syncthreads();
        #pragma unroll
        for (int it = 0; it < 2; ++it) {
            int idx = tid + it * 256;
            int kk = idx & 63, dg = idx >> 6;
            bf16x8 vv = *(const bf16x8*)(Vh + (c0 + kk) * DHN + dg * 8);
            #pragma unroll
            for (int j = 0; j < 8; ++j)
                Vt[dg * 8 + j][kk] = (u16)vv[j];
        }
        __syncthreads();
        #pragma unroll
        for (int ks = 0; ks < 2; ++ks) {
            bf16x8 a  = *(const bf16x8*)(&sb[mt * 16 + lr][c0 + ks * 32 + kb8]);
            bf16x8 b0 = *(const bf16x8*)(&Vt[ntp * 16 + lr][ks * 32 + kb8]);
            bf16x8 b1 = *(const bf16x8*)(&Vt[(ntp + 1) * 16 + lr][ks * 32 + kb8]);
            acc0 = __builtin_amdgcn_mfma_f32_16x16x32_bf16(a, b0, acc0, 0, 0, 0);
            acc1 = __builtin_amdgcn_mfma_f32_16x16x32_bf16(a, b1, acc1, 0, 0, 0);
        }
    }
    const int srow = q0 + mt * 16 + lg * 4;
    #pragma unroll
    for (int r = 0; r < 4; ++r) {
        float* op = out + (size_t)(b * SN + srow + r) * DN + h * DHN;
        op[ntp * 16 + lr]       = acc0[r];
        op[(ntp + 1) * 16 + lr] = acc1[r];
    }
}

// ---------------------------------------------------------------------------
extern "C" void kernel_launch(void* const* d_in, const int* in_sizes, int n_in,
                              void* d_out, int out_size, void* d_ws, size_t ws_size,
                              hipStream_t stream) {
    const float* X    = (const float*)d_in[0];
    const float* mask = (const float*)d_in[1];
    const float* Wq   = (const float*)d_in[2];
    const float* bq   = (const float*)d_in[3];
    const float* Wk   = (const float*)d_in[4];
    const float* bk   = (const float*)d_in[5];
    const float* Wv   = (const float*)d_in[6];
    const float* bv   = (const float*)d_in[7];
    const float* ew1  = (const float*)d_in[8];
    const float* eb1  = (const float*)d_in[9];
    const float* ew2  = (const float*)d_in[10];
    const float* eb2  = (const float*)d_in[11];
    const float* iw1  = (const float*)d_in[12];
    const float* ib1  = (const float*)d_in[13];
    const float* iw2  = (const float*)d_in[14];
    const float* ib2  = (const float*)d_in[15];
    float* out = (float*)d_out;

    u16* Xb  = (u16*)d_ws;
    u16* Wqb = Xb + (size_t)(BN * SN) * DN;
    u16* Wkb = Wqb + DN * DN;
    u16* Wvb = Wkb + DN * DN;
    u16* Qb  = Wvb + DN * DN;
    const size_t per = (size_t)BN * NHN * SN * DHN;
    u16* Kb2 = Qb + per;
    u16* Vb2 = Kb2 + per;

    dim3 gc(1536, 4);
    cvt_bf16<<<gc, 256, 0, stream>>>(X, Wq, Wk, Wv, Xb, Wqb, Wkb, Wvb);

    dim3 g1(36, 16);                       // n-tiles (3*768/64), m-tiles (2048/128)
    qkv_mfma<<<g1, 256, 0, stream>>>(Xb, Wqb, Wkb, Wvb, bq, bk, bv, Qb, Kb2, Vb2);

    dim3 g2(SN / 32, BN * NHN);            // (16, 48)
    attn_mfma<<<g2, 256, 0, stream>>>(Qb, Kb2, Vb2, mask,
                                      ew1, eb1, ew2, eb2,
                                      iw1, ib1, iw2, ib2, out);
}

// Round 4
// 77.022 us; speedup vs baseline: 4.6967x; 1.0667x over previous
//
#include <hip/hip_runtime.h>
#include <math.h>

typedef unsigned short u16;
typedef short bf16x8 __attribute__((ext_vector_type(8)));
typedef float f32x4 __attribute__((ext_vector_type(4)));
typedef _Float16 h2 __attribute__((ext_vector_type(2)));

#define BN 4
#define SN 512
#define DN 768
#define NHN 12
#define DHN 64
#define EXPN 32
#define INVN 64

__device__ __forceinline__ u16 f2b(float f) {
    union { float f; unsigned int u; } v; v.f = f;
    unsigned int r = v.u + 0x7FFFu + ((v.u >> 16) & 1u);
    return (u16)(r >> 16);
}
__device__ __forceinline__ float b2f(u16 h) {
    union { unsigned int u; float f; } v; v.u = ((unsigned int)h) << 16;
    return v.f;
}

#define GLD16(g, l) __builtin_amdgcn_global_load_lds( \
    (__attribute__((address_space(1))) const void*)(g), \
    (__attribute__((address_space(3))) void*)(l), 16, 0, 0)

// ---------------------------------------------------------------------------
// Kernel 0: f32 -> bf16 conversion of X and the three weight matrices.
// ---------------------------------------------------------------------------
__global__ __launch_bounds__(256) void cvt_bf16(
    const float* __restrict__ X, const float* __restrict__ Wq,
    const float* __restrict__ Wk, const float* __restrict__ Wv,
    u16* __restrict__ Xb, u16* __restrict__ Wqb,
    u16* __restrict__ Wkb, u16* __restrict__ Wvb)
{
    const float* s; u16* d; int n;
    switch (blockIdx.y) {
        case 0:  s = X;  d = Xb;  n = (BN * SN) * DN; break;
        case 1:  s = Wq; d = Wqb; n = DN * DN; break;
        case 2:  s = Wk; d = Wkb; n = DN * DN; break;
        default: s = Wv; d = Wvb; n = DN * DN; break;
    }
    int i = (blockIdx.x * 256 + threadIdx.x) * 4;
    if (i < n) {
        float4 v = *(const float4*)&s[i];
        unsigned int lo = (unsigned)f2b(v.x) | ((unsigned)f2b(v.y) << 16);
        unsigned int hi = (unsigned)f2b(v.z) | ((unsigned)f2b(v.w) << 16);
        *(uint2*)&d[i] = make_uint2(lo, hi);
    }
}

// ---------------------------------------------------------------------------
// Kernel 1: fused QKV projection (m97-style). BM=128 x BN=64, BK=32, 4 waves,
// global_load_lds staging, XOR-swizzled LDS. V is stored TRANSPOSED
// [B,NH,DH,S] so the attention PV step needs no LDS transpose.
// ---------------------------------------------------------------------------
__global__ __launch_bounds__(256) void qkv_mfma(
    const u16* __restrict__ Xb,
    const u16* __restrict__ Wqb, const u16* __restrict__ Wkb, const u16* __restrict__ Wvb,
    const float* __restrict__ bq, const float* __restrict__ bk, const float* __restrict__ bv,
    u16* __restrict__ Qb, u16* __restrict__ Kb, u16* __restrict__ Vtr)
{
    __shared__ __align__(16) u16 As[128 * 32];
    __shared__ __align__(16) u16 Bs[64 * 32];

    const int tid = threadIdx.x, w = tid >> 6, l = tid & 63;
    const int lr = l & 15, lg = l >> 4;
    const int m0 = blockIdx.y * 128;
    const int nsel = blockIdx.x / 12;
    const int n0l = (blockIdx.x % 12) * 64;
    const u16* W = (nsel == 0) ? Wqb : (nsel == 1) ? Wkb : Wvb;
    const float* bias = (nsel == 0) ? bq : (nsel == 1) ? bk : bv;
    u16* out = (nsel == 0) ? Qb : (nsel == 1) ? Kb : Vtr;

    const int wm = w >> 1, wn = w & 1;

    const int oA0 = tid * 16;
    const int rA0 = oA0 >> 6, sA0 = (oA0 >> 4) & 3;
    const int cA0 = (sA0 ^ ((rA0 >> 1) & 3)) * 8;
    const int oA1 = oA0 + 4096;
    const int rA1 = oA1 >> 6, sA1 = (oA1 >> 4) & 3;
    const int cA1 = (sA1 ^ ((rA1 >> 1) & 3)) * 8;
    const u16* gA0 = Xb + (m0 + rA0) * DN + cA0;
    const u16* gA1 = Xb + (m0 + rA1) * DN + cA1;
    const u16* gB  = W + (n0l + rA0) * DN + cA0;

    int offA[4], offB[2];
    #pragma unroll
    for (int mi = 0; mi < 4; ++mi) {
        int row = wm * 64 + mi * 16 + lr;
        offA[mi] = row * 64 + ((lg ^ ((row >> 1) & 3)) * 16);
    }
    #pragma unroll
    for (int ni = 0; ni < 2; ++ni) {
        int row = wn * 32 + ni * 16 + lr;
        offB[ni] = row * 64 + ((lg ^ ((row >> 1) & 3)) * 16);
    }

    f32x4 acc[4][2];
    #pragma unroll
    for (int mi = 0; mi < 4; ++mi)
        #pragma unroll
        for (int ni = 0; ni < 2; ++ni) acc[mi][ni] = (f32x4){0.f, 0.f, 0.f, 0.f};

    for (int k0 = 0; k0 < DN; k0 += 32) {
        __syncthreads();
        GLD16(gA0 + k0, (char*)As + oA0);
        GLD16(gA1 + k0, (char*)As + oA1);
        GLD16(gB  + k0, (char*)Bs + oA0);
        __syncthreads();

        bf16x8 af[4], bff[2];
        #pragma unroll
        for (int mi = 0; mi < 4; ++mi) af[mi] = *(const bf16x8*)((const char*)As + offA[mi]);
        #pragma unroll
        for (int ni = 0; ni < 2; ++ni) bff[ni] = *(const bf16x8*)((const char*)Bs + offB[ni]);
        #pragma unroll
        for (int mi = 0; mi < 4; ++mi)
            #pragma unroll
            for (int ni = 0; ni < 2; ++ni)
                acc[mi][ni] = __builtin_amdgcn_mfma_f32_16x16x32_bf16(af[mi], bff[ni], acc[mi][ni], 0, 0, 0);
    }

    if (nsel < 2) {
        // Q/K: [B,NH,S,DH]
        #pragma unroll
        for (int ni = 0; ni < 2; ++ni) {
            int col = n0l + wn * 32 + ni * 16 + lr;
            float bc = bias[col];
            int hh = col >> 6, dh = col & 63;
            #pragma unroll
            for (int mi = 0; mi < 4; ++mi) {
                #pragma unroll
                for (int r = 0; r < 4; ++r) {
                    int m = m0 + wm * 64 + mi * 16 + lg * 4 + r;
                    int bi = m >> 9, srow = m & 511;
                    out[(((bi * NHN + hh) * SN) + srow) * DHN + dh] = f2b(acc[mi][ni][r] + bc);
                }
            }
        }
    } else {
        // V: transposed [B,NH,DH,S]; 4 consecutive srow -> one 8B store
        #pragma unroll
        for (int ni = 0; ni < 2; ++ni) {
            int col = n0l + wn * 32 + ni * 16 + lr;
            float bc = bias[col];
            int hh = col >> 6, dh = col & 63;
            #pragma unroll
            for (int mi = 0; mi < 4; ++mi) {
                int m = m0 + wm * 64 + mi * 16 + lg * 4;
                int bi = m >> 9, srow = m & 511;
                ushort4 pk;
                pk.x = f2b(acc[mi][ni][0] + bc);
                pk.y = f2b(acc[mi][ni][1] + bc);
                pk.z = f2b(acc[mi][ni][2] + bc);
                pk.w = f2b(acc[mi][ni][3] + bc);
                *(ushort4*)&out[((size_t)(bi * NHN + hh) * DHN + dh) * SN + srow] = pk;
            }
        }
    }
}

// ---------------------------------------------------------------------------
// Kernel 2: attention. MFMA QK^T -> bf16 scores in LDS -> packed-f16
// fit_softmax -> MFMA PV with direct-global transposed-V fragments.
// ---------------------------------------------------------------------------
__global__ __launch_bounds__(256) void attn_mfma(
    const u16* __restrict__ Qb, const u16* __restrict__ Kb, const u16* __restrict__ Vtr,
    const float* __restrict__ mask,
    const float* __restrict__ ew1, const float* __restrict__ eb1,
    const float* __restrict__ ew2, const float* __restrict__ eb2,
    const float* __restrict__ iw1, const float* __restrict__ ib1,
    const float* __restrict__ iw2, const float* __restrict__ ib2,
    float* __restrict__ out)
{
    __shared__ __align__(16) u16 sb[32][528];
    __shared__ float ms[SN];
    __shared__ h2 wE1h[EXPN], wEb1h[EXPN], wE2h[EXPN];
    __shared__ float wI1[INVN], wIb1[INVN], wI2[INVN];
    __shared__ float refs[32];
    __shared__ float scal[2];

    const int tid = threadIdx.x, w = tid >> 6, l = tid & 63;
    const int lr = l & 15, lg = l >> 4, kb8 = lg * 8;
    const int bh = blockIdx.y, b = bh / NHN, h = bh % NHN;
    const int q0 = blockIdx.x * 32;
    const u16* Qh = Qb + (size_t)bh * SN * DHN;
    const u16* Kh = Kb + (size_t)bh * SN * DHN;
    const u16* VTh = Vtr + (size_t)bh * DHN * SN;

    if (tid < EXPN) {
        float a = ew1[tid], bb = eb1[tid], c = ew2[tid];
        wE1h[tid]  = (h2){(_Float16)a, (_Float16)a};
        wEb1h[tid] = (h2){(_Float16)bb, (_Float16)bb};
        wE2h[tid]  = (h2){(_Float16)c, (_Float16)c};
    } else if (tid >= 64 && tid < 64 + INVN) {
        int t = tid - 64; wI1[t] = iw1[t]; wIb1[t] = ib1[t]; wI2[t] = iw2[t];
    }
    if (tid == 255) { scal[0] = eb2[0]; scal[1] = ib2[0]; }
    for (int i = tid; i < SN; i += 256) ms[i] = mask[b * SN + i];
    __syncthreads();

    // ---- phase 1: scores = QK^T/8 + mask (MFMA) ----
    const int mt = w & 1, nh2 = w >> 1;
    const int arow = q0 + mt * 16 + lr;
    bf16x8 aq0 = *(const bf16x8*)(Qh + arow * DHN + kb8);
    bf16x8 aq1 = *(const bf16x8*)(Qh + arow * DHN + 32 + kb8);
    #pragma unroll 2
    for (int i = 0; i < 16; ++i) {
        int col0 = (nh2 * 16 + i) * 16;
        const u16* kp = Kh + (col0 + lr) * DHN + kb8;
        bf16x8 b0 = *(const bf16x8*)(kp);
        bf16x8 b1 = *(const bf16x8*)(kp + 32);
        f32x4 d = {0.f, 0.f, 0.f, 0.f};
        d = __builtin_amdgcn_mfma_f32_16x16x32_bf16(aq0, b0, d, 0, 0, 0);
        d = __builtin_amdgcn_mfma_f32_16x16x32_bf16(aq1, b1, d, 0, 0, 0);
        float mv = ms[col0 + lr];
        int rb = mt * 16 + lg * 4;
        #pragma unroll
        for (int r = 0; r < 4; ++r)
            sb[rb + r][col0 + lr] = f2b(d[r] * 0.125f + mv);
    }
    if (w == 0) {
        bf16x8 a00 = *(const bf16x8*)(Qh + kb8);
        bf16x8 a01 = *(const bf16x8*)(Qh + 32 + kb8);
        #pragma unroll
        for (int t = 0; t < 2; ++t) {
            int col0 = q0 + t * 16;
            const u16* kp = Kh + (col0 + lr) * DHN + kb8;
            bf16x8 b0 = *(const bf16x8*)(kp);
            bf16x8 b1 = *(const bf16x8*)(kp + 32);
            f32x4 d = {0.f, 0.f, 0.f, 0.f};
            d = __builtin_amdgcn_mfma_f32_16x16x32_bf16(a00, b0, d, 0, 0, 0);
            d = __builtin_amdgcn_mfma_f32_16x16x32_bf16(a01, b1, d, 0, 0, 0);
            if (lg == 0) refs[t * 16 + lr] = d[0] * 0.125f + ms[col0 + lr];
        }
    }
    __syncthreads();

    // ---- phase 2: fit_softmax, packed f16 hinge MLP ----
    const float eb2v = scal[0], ib2v = scal[1];
    const h2 zzero = {(_Float16)0.f, (_Float16)0.f};
    for (int rr = 0; rr < 8; ++rr) {
        const int r = w * 8 + rr;
        const float refm1 = refs[r] - 1.0f;
        float tp[8];
        #pragma unroll
        for (int j = 0; j < 8; ++j) {
            float x = b2f(sb[r][l + 64 * j]);
            tp[j] = fminf(x - refm1, 3.0f);
        }
        h2 tph[4], e2[4];
        const _Float16 einit = (_Float16)eb2v;
        #pragma unroll
        for (int p = 0; p < 4; ++p) {
            tph[p] = (h2){(_Float16)tp[2 * p], (_Float16)tp[2 * p + 1]};
            e2[p] = (h2){einit, einit};
        }
        #pragma unroll 4
        for (int n = 0; n < EXPN; ++n) {
            h2 w1 = wE1h[n], bb1 = wEb1h[n], w2 = wE2h[n];
            #pragma unroll
            for (int p = 0; p < 4; ++p) {
                h2 t = __builtin_elementwise_fma(tph[p], w1, bb1);
                t = __builtin_elementwise_max(t, zzero);
                e2[p] = __builtin_elementwise_fma(t, w2, e2[p]);
            }
        }
        float xup[8];
        float part = 0.f;
        #pragma unroll
        for (int p = 0; p < 4; ++p) {
            float ea = (float)e2[p][0], eb = (float)e2[p][1];
            xup[2 * p]     = (tp[2 * p]     > -20.0f) ? ea : 0.f;
            xup[2 * p + 1] = (tp[2 * p + 1] > -20.0f) ? eb : 0.f;
            part += xup[2 * p] + xup[2 * p + 1];
        }
        #pragma unroll
        for (int s = 32; s > 0; s >>= 1) part += __shfl_xor(part, s);
        float hu = fmaxf(part * wI1[l] + wIb1[l], 0.f) * wI2[l];
        #pragma unroll
        for (int s = 32; s > 0; s >>= 1) hu += __shfl_xor(hu, s);
        const float pinv = hu + ib2v;
        float p2 = 0.f;
        #pragma unroll
        for (int j = 0; j < 8; ++j) { xup[j] *= pinv; p2 += xup[j]; }
        #pragma unroll
        for (int s = 32; s > 0; s >>= 1) p2 += __shfl_xor(p2, s);
        float hu2 = fmaxf(p2 * wI1[l] + wIb1[l], 0.f) * wI2[l];
        #pragma unroll
        for (int s = 32; s > 0; s >>= 1) hu2 += __shfl_xor(hu2, s);
        const float pinv2 = hu2 + ib2v;
        const float scale = (p2 > 1.5f) ? pinv2 : 1.0f;
        #pragma unroll
        for (int j = 0; j < 8; ++j)
            sb[r][l + 64 * j] = f2b(xup[j] * scale);
    }
    __syncthreads();

    // ---- phase 3: ctx = probs @ V, V^T fragments direct from global ----
    f32x4 acc0 = {0.f, 0.f, 0.f, 0.f}, acc1 = {0.f, 0.f, 0.f, 0.f};
    const int ntp = (w >> 1) * 2;
    const u16* vp0 = VTh + (ntp * 16 + lr) * SN + kb8;
    const u16* vp1 = VTh + ((ntp + 1) * 16 + lr) * SN + kb8;
    const u16* sp  = &sb[mt * 16 + lr][kb8];
    #pragma unroll 4
    for (int kk0 = 0; kk0 < SN; kk0 += 32) {
        bf16x8 a  = *(const bf16x8*)(sp + kk0);
        bf16x8 b0 = *(const bf16x8*)(vp0 + kk0);
        bf16x8 b1 = *(const bf16x8*)(vp1 + kk0);
        acc0 = __builtin_amdgcn_mfma_f32_16x16x32_bf16(a, b0, acc0, 0, 0, 0);
        acc1 = __builtin_amdgcn_mfma_f32_16x16x32_bf16(a, b1, acc1, 0, 0, 0);
    }
    const int srow = q0 + mt * 16 + lg * 4;
    #pragma unroll
    for (int r = 0; r < 4; ++r) {
        float* op = out + (size_t)(b * SN + srow + r) * DN + h * DHN;
        op[ntp * 16 + lr]       = acc0[r];
        op[(ntp + 1) * 16 + lr] = acc1[r];
    }
}

// ---------------------------------------------------------------------------
extern "C" void kernel_launch(void* const* d_in, const int* in_sizes, int n_in,
                              void* d_out, int out_size, void* d_ws, size_t ws_size,
                              hipStream_t stream) {
    const float* X    = (const float*)d_in[0];
    const float* mask = (const float*)d_in[1];
    const float* Wq   = (const float*)d_in[2];
    const float* bq   = (const float*)d_in[3];
    const float* Wk   = (const float*)d_in[4];
    const float* bk   = (const float*)d_in[5];
    const float* Wv   = (const float*)d_in[6];
    const float* bv   = (const float*)d_in[7];
    const float* ew1  = (const float*)d_in[8];
    const float* eb1  = (const float*)d_in[9];
    const float* ew2  = (const float*)d_in[10];
    const float* eb2  = (const float*)d_in[11];
    const float* iw1  = (const float*)d_in[12];
    const float* ib1  = (const float*)d_in[13];
    const float* iw2  = (const float*)d_in[14];
    const float* ib2  = (const float*)d_in[15];
    float* out = (float*)d_out;

    u16* Xb  = (u16*)d_ws;
    u16* Wqb = Xb + (size_t)(BN * SN) * DN;
    u16* Wkb = Wqb + DN * DN;
    u16* Wvb = Wkb + DN * DN;
    u16* Qb  = Wvb + DN * DN;
    const size_t per = (size_t)BN * NHN * SN * DHN;
    u16* Kb2 = Qb + per;
    u16* Vb2 = Kb2 + per;   // holds V^T [B,NH,DH,S]

    dim3 gc(1536, 4);
    cvt_bf16<<<gc, 256, 0, stream>>>(X, Wq, Wk, Wv, Xb, Wqb, Wkb, Wvb);

    dim3 g1(36, 16);
    qkv_mfma<<<g1, 256, 0, stream>>>(Xb, Wqb, Wkb, Wvb, bq, bk, bv, Qb, Kb2, Vb2);

    dim3 g2(SN / 32, BN * NHN);
    attn_mfma<<<g2, 256, 0, stream>>>(Qb, Kb2, Vb2, mask,
                                      ew1, eb1, ew2, eb2,
                                      iw1, ib1, iw2, ib2, out);
}

// Round 5
// 65.665 us; speedup vs baseline: 5.5090x; 1.1730x over previous
//
#include <hip/hip_runtime.h>
#include <math.h>

typedef unsigned short u16;
typedef short bf16x8 __attribute__((ext_vector_type(8)));
typedef float f32x4 __attribute__((ext_vector_type(4)));
typedef _Float16 h2 __attribute__((ext_vector_type(2)));

#define BN 4
#define SN 512
#define DN 768
#define NHN 12
#define DHN 64
#define EXPN 32
#define INVN 64

__device__ __forceinline__ u16 f2b(float f) {
    union { float f; unsigned int u; } v; v.f = f;
    unsigned int r = v.u + 0x7FFFu + ((v.u >> 16) & 1u);
    return (u16)(r >> 16);
}
__device__ __forceinline__ float b2f(u16 h) {
    union { unsigned int u; float f; } v; v.u = ((unsigned int)h) << 16;
    return v.f;
}

#define GLD16(g, l) __builtin_amdgcn_global_load_lds( \
    (__attribute__((address_space(1))) const void*)(g), \
    (__attribute__((address_space(3))) void*)(l), 16, 0, 0)

// ---------------------------------------------------------------------------
// Kernel 0: f32 -> bf16 conversion of X and the three weight matrices.
// ---------------------------------------------------------------------------
__global__ __launch_bounds__(256) void cvt_bf16(
    const float* __restrict__ X, const float* __restrict__ Wq,
    const float* __restrict__ Wk, const float* __restrict__ Wv,
    u16* __restrict__ Xb, u16* __restrict__ Wqb,
    u16* __restrict__ Wkb, u16* __restrict__ Wvb)
{
    const float* s; u16* d; int n;
    switch (blockIdx.y) {
        case 0:  s = X;  d = Xb;  n = (BN * SN) * DN; break;
        case 1:  s = Wq; d = Wqb; n = DN * DN; break;
        case 2:  s = Wk; d = Wkb; n = DN * DN; break;
        default: s = Wv; d = Wvb; n = DN * DN; break;
    }
    int i = (blockIdx.x * 256 + threadIdx.x) * 4;
    if (i < n) {
        float4 v = *(const float4*)&s[i];
        unsigned int lo = (unsigned)f2b(v.x) | ((unsigned)f2b(v.y) << 16);
        unsigned int hi = (unsigned)f2b(v.z) | ((unsigned)f2b(v.w) << 16);
        *(uint2*)&d[i] = make_uint2(lo, hi);
    }
}

// ---------------------------------------------------------------------------
// Kernel 1: fused QKV projection (m97-style). BM=128 x BN=64, BK=32, 4 waves,
// global_load_lds staging, XOR-swizzled LDS. V stored TRANSPOSED [B,NH,DH,S].
// ---------------------------------------------------------------------------
__global__ __launch_bounds__(256) void qkv_mfma(
    const u16* __restrict__ Xb,
    const u16* __restrict__ Wqb, const u16* __restrict__ Wkb, const u16* __restrict__ Wvb,
    const float* __restrict__ bq, const float* __restrict__ bk, const float* __restrict__ bv,
    u16* __restrict__ Qb, u16* __restrict__ Kb, u16* __restrict__ Vtr)
{
    __shared__ __align__(16) u16 As[128 * 32];
    __shared__ __align__(16) u16 Bs[64 * 32];

    const int tid = threadIdx.x, w = tid >> 6, l = tid & 63;
    const int lr = l & 15, lg = l >> 4;
    const int m0 = blockIdx.y * 128;
    const int nsel = blockIdx.x / 12;
    const int n0l = (blockIdx.x % 12) * 64;
    const u16* W = (nsel == 0) ? Wqb : (nsel == 1) ? Wkb : Wvb;
    const float* bias = (nsel == 0) ? bq : (nsel == 1) ? bk : bv;
    u16* out = (nsel == 0) ? Qb : (nsel == 1) ? Kb : Vtr;

    const int wm = w >> 1, wn = w & 1;

    const int oA0 = tid * 16;
    const int rA0 = oA0 >> 6, sA0 = (oA0 >> 4) & 3;
    const int cA0 = (sA0 ^ ((rA0 >> 1) & 3)) * 8;
    const int oA1 = oA0 + 4096;
    const int rA1 = oA1 >> 6, sA1 = (oA1 >> 4) & 3;
    const int cA1 = (sA1 ^ ((rA1 >> 1) & 3)) * 8;
    const u16* gA0 = Xb + (m0 + rA0) * DN + cA0;
    const u16* gA1 = Xb + (m0 + rA1) * DN + cA1;
    const u16* gB  = W + (n0l + rA0) * DN + cA0;

    int offA[4], offB[2];
    #pragma unroll
    for (int mi = 0; mi < 4; ++mi) {
        int row = wm * 64 + mi * 16 + lr;
        offA[mi] = row * 64 + ((lg ^ ((row >> 1) & 3)) * 16);
    }
    #pragma unroll
    for (int ni = 0; ni < 2; ++ni) {
        int row = wn * 32 + ni * 16 + lr;
        offB[ni] = row * 64 + ((lg ^ ((row >> 1) & 3)) * 16);
    }

    f32x4 acc[4][2];
    #pragma unroll
    for (int mi = 0; mi < 4; ++mi)
        #pragma unroll
        for (int ni = 0; ni < 2; ++ni) acc[mi][ni] = (f32x4){0.f, 0.f, 0.f, 0.f};

    for (int k0 = 0; k0 < DN; k0 += 32) {
        __syncthreads();
        GLD16(gA0 + k0, (char*)As + oA0);
        GLD16(gA1 + k0, (char*)As + oA1);
        GLD16(gB  + k0, (char*)Bs + oA0);
        __syncthreads();

        bf16x8 af[4], bff[2];
        #pragma unroll
        for (int mi = 0; mi < 4; ++mi) af[mi] = *(const bf16x8*)((const char*)As + offA[mi]);
        #pragma unroll
        for (int ni = 0; ni < 2; ++ni) bff[ni] = *(const bf16x8*)((const char*)Bs + offB[ni]);
        #pragma unroll
        for (int mi = 0; mi < 4; ++mi)
            #pragma unroll
            for (int ni = 0; ni < 2; ++ni)
                acc[mi][ni] = __builtin_amdgcn_mfma_f32_16x16x32_bf16(af[mi], bff[ni], acc[mi][ni], 0, 0, 0);
    }

    if (nsel < 2) {
        #pragma unroll
        for (int ni = 0; ni < 2; ++ni) {
            int col = n0l + wn * 32 + ni * 16 + lr;
            float bc = bias[col];
            int hh = col >> 6, dh = col & 63;
            #pragma unroll
            for (int mi = 0; mi < 4; ++mi) {
                #pragma unroll
                for (int r = 0; r < 4; ++r) {
                    int m = m0 + wm * 64 + mi * 16 + lg * 4 + r;
                    int bi = m >> 9, srow = m & 511;
                    out[(((bi * NHN + hh) * SN) + srow) * DHN + dh] = f2b(acc[mi][ni][r] + bc);
                }
            }
        }
    } else {
        #pragma unroll
        for (int ni = 0; ni < 2; ++ni) {
            int col = n0l + wn * 32 + ni * 16 + lr;
            float bc = bias[col];
            int hh = col >> 6, dh = col & 63;
            #pragma unroll
            for (int mi = 0; mi < 4; ++mi) {
                int m = m0 + wm * 64 + mi * 16 + lg * 4;
                int bi = m >> 9, srow = m & 511;
                ushort4 pk;
                pk.x = f2b(acc[mi][ni][0] + bc);
                pk.y = f2b(acc[mi][ni][1] + bc);
                pk.z = f2b(acc[mi][ni][2] + bc);
                pk.w = f2b(acc[mi][ni][3] + bc);
                *(ushort4*)&out[((size_t)(bi * NHN + hh) * DHN + dh) * SN + srow] = pk;
            }
        }
    }
}

// ---------------------------------------------------------------------------
// Kernel 2: attention, QBLK=16, fused score+MLP. One block per (head, 16 q
// rows), 4 waves; wave w owns a 128-key column strip of QK^T (with the MLP
// fused on the register scores) and dh columns [16w,16w+16) of PV.
// X_up stored bf16 in XOR-swizzled LDS [16][512]; row scale applied to the
// PV f32 accumulator. partition_p2 = pinv*partition (exact identity).
// ---------------------------------------------------------------------------
__global__ __launch_bounds__(256) void attn_mfma(
    const u16* __restrict__ Qb, const u16* __restrict__ Kb, const u16* __restrict__ Vtr,
    const float* __restrict__ mask,
    const float* __restrict__ ew1, const float* __restrict__ eb1,
    const float* __restrict__ ew2, const float* __restrict__ eb2,
    const float* __restrict__ iw1, const float* __restrict__ ib1,
    const float* __restrict__ iw2, const float* __restrict__ ib2,
    float* __restrict__ out)
{
    __shared__ __align__(16) u16 sb[16 * 512];     // X_up tile, swizzled, 16 KB
    __shared__ float ms[SN];
    __shared__ h2 wE1h[EXPN], wEb1h[EXPN], wE2h[EXPN];
    __shared__ float wI1[INVN], wIb1[INVN], wI2[INVN];
    __shared__ float partw[4][16];
    __shared__ float scale_s[16];
    __shared__ float scal[2];

    const int tid = threadIdx.x, w = tid >> 6, l = tid & 63;
    const int lr = l & 15, lg = l >> 4, kb8 = lg * 8;
    const int bh = blockIdx.y, b = bh / NHN, h = bh % NHN;
    const int q0 = blockIdx.x * 16;
    const u16* Qh = Qb + (size_t)bh * SN * DHN;
    const u16* Kh = Kb + (size_t)bh * SN * DHN;
    const u16* VTh = Vtr + (size_t)bh * DHN * SN;

    if (tid < EXPN) {
        float a = ew1[tid], bb = eb1[tid], c = ew2[tid];
        wE1h[tid]  = (h2){(_Float16)a, (_Float16)a};
        wEb1h[tid] = (h2){(_Float16)bb, (_Float16)bb};
        wE2h[tid]  = (h2){(_Float16)c, (_Float16)c};
    } else if (tid >= 64 && tid < 64 + INVN) {
        int t = tid - 64; wI1[t] = iw1[t]; wIb1[t] = ib1[t]; wI2[t] = iw2[t];
    }
    if (tid == 255) { scal[0] = eb2[0]; scal[1] = ib2[0]; }
    for (int i = tid; i < SN; i += 256) ms[i] = mask[b * SN + i];
    __syncthreads();

    const float eb2v = scal[0], ib2v = scal[1];

    // Q A-fragments (rows q0..q0+15)
    bf16x8 aq0 = *(const bf16x8*)(Qh + (q0 + lr) * DHN + kb8);
    bf16x8 aq1 = *(const bf16x8*)(Qh + (q0 + lr) * DHN + 32 + kb8);

    // refs: score[b,h,0,q0+lr] via Q0-replicated A (redundant per wave)
    float myref[4];
    {
        bf16x8 a00 = *(const bf16x8*)(Qh + kb8);
        bf16x8 a01 = *(const bf16x8*)(Qh + 32 + kb8);
        const u16* kp = Kh + (q0 + lr) * DHN + kb8;
        bf16x8 b0 = *(const bf16x8*)(kp);
        bf16x8 b1 = *(const bf16x8*)(kp + 32);
        f32x4 d = {0.f, 0.f, 0.f, 0.f};
        d = __builtin_amdgcn_mfma_f32_16x16x32_bf16(a00, b0, d, 0, 0, 0);
        d = __builtin_amdgcn_mfma_f32_16x16x32_bf16(a01, b1, d, 0, 0, 0);
        float refc = d[0] * 0.125f + ms[q0 + lr];   // valid on lanes lg==0
        #pragma unroll
        for (int r = 0; r < 4; ++r) myref[r] = __shfl(refc, lg * 4 + r);
    }

    // ---- fused QK^T + exp-MLP over this wave's 128-key strip ----
    char* sbb = (char*)sb;
    float part[4] = {0.f, 0.f, 0.f, 0.f};
    const h2 zzero = {(_Float16)0.f, (_Float16)0.f};
    const _Float16 einit = (_Float16)eb2v;
    #pragma unroll 2
    for (int i = 0; i < 8; ++i) {
        const int col0 = w * 128 + i * 16;
        const u16* kp = Kh + (col0 + lr) * DHN + kb8;
        bf16x8 b0 = *(const bf16x8*)(kp);
        bf16x8 b1 = *(const bf16x8*)(kp + 32);
        f32x4 d = {0.f, 0.f, 0.f, 0.f};
        d = __builtin_amdgcn_mfma_f32_16x16x32_bf16(aq0, b0, d, 0, 0, 0);
        d = __builtin_amdgcn_mfma_f32_16x16x32_bf16(aq1, b1, d, 0, 0, 0);
        const float mv = ms[col0 + lr];
        float tp[4];
        #pragma unroll
        for (int r = 0; r < 4; ++r)
            tp[r] = fminf(d[r] * 0.125f + mv - (myref[r] - 1.0f), 3.0f);
        h2 t0 = {(_Float16)tp[0], (_Float16)tp[1]};
        h2 t1 = {(_Float16)tp[2], (_Float16)tp[3]};
        h2 e0 = {einit, einit}, e1 = {einit, einit};
        #pragma unroll 4
        for (int n = 0; n < EXPN; ++n) {
            h2 w1 = wE1h[n], bb1 = wEb1h[n], w2 = wE2h[n];
            h2 u0 = __builtin_elementwise_max(__builtin_elementwise_fma(t0, w1, bb1), zzero);
            h2 u1 = __builtin_elementwise_max(__builtin_elementwise_fma(t1, w1, bb1), zzero);
            e0 = __builtin_elementwise_fma(u0, w2, e0);
            e1 = __builtin_elementwise_fma(u1, w2, e1);
        }
        float ev[4] = {(float)e0[0], (float)e0[1], (float)e1[0], (float)e1[1]};
        #pragma unroll
        for (int r = 0; r < 4; ++r) {
            float xu = (tp[r] > -20.0f) ? ev[r] : 0.f;
            part[r] += xu;
            int row = lg * 4 + r;
            *(u16*)(sbb + row * 1024 + (((col0 + lr) * 2) ^ ((row & 7) << 4))) = f2b(xu);
        }
    }
    // partition: reduce across the 16 lanes of each lg group
    #pragma unroll
    for (int r = 0; r < 4; ++r) {
        #pragma unroll
        for (int s = 1; s < 16; s <<= 1) part[r] += __shfl_xor(part[r], s);
    }
    if (lr == 0) {
        #pragma unroll
        for (int r = 0; r < 4; ++r) partw[w][lg * 4 + r] = part[r];
    }
    __syncthreads();

    // ---- row scales (wave w: rows 4w..4w+3), inv MLP lane-parallel ----
    #pragma unroll
    for (int rr = 0; rr < 4; ++rr) {
        const int row = w * 4 + rr;
        const float pt = partw[0][row] + partw[1][row] + partw[2][row] + partw[3][row];
        float hu = fmaxf(pt * wI1[l] + wIb1[l], 0.f) * wI2[l];
        #pragma unroll
        for (int s = 32; s > 0; s >>= 1) hu += __shfl_xor(hu, s);
        const float pinv = hu + ib2v;
        const float p2 = pt * pinv;                 // == sum(X_up*pinv) exactly
        float hu2 = fmaxf(p2 * wI1[l] + wIb1[l], 0.f) * wI2[l];
        #pragma unroll
        for (int s = 32; s > 0; s >>= 1) hu2 += __shfl_xor(hu2, s);
        const float pinv2 = hu2 + ib2v;
        if (l == 0) scale_s[row] = pinv * ((p2 > 1.5f) ? pinv2 : 1.0f);
    }

    // ---- PV: wave w owns dh cols [16w,16w+16), K=512 ----
    f32x4 acc = {0.f, 0.f, 0.f, 0.f};
    const u16* vp = VTh + (w * 16 + lr) * SN + kb8;
    const int swz = (lr & 7) << 4;
    #pragma unroll 4
    for (int k0 = 0; k0 < SN; k0 += 32) {
        bf16x8 a  = *(const bf16x8*)(sbb + lr * 1024 + (((k0 + kb8) * 2) ^ swz));
        bf16x8 bv = *(const bf16x8*)(vp + k0);
        acc = __builtin_amdgcn_mfma_f32_16x16x32_bf16(a, bv, acc, 0, 0, 0);
    }
    __syncthreads();
    #pragma unroll
    for (int r = 0; r < 4; ++r) {
        const float sc = scale_s[lg * 4 + r];
        out[(size_t)(b * SN + q0 + lg * 4 + r) * DN + h * DHN + w * 16 + lr] = acc[r] * sc;
    }
}

// ---------------------------------------------------------------------------
extern "C" void kernel_launch(void* const* d_in, const int* in_sizes, int n_in,
                              void* d_out, int out_size, void* d_ws, size_t ws_size,
                              hipStream_t stream) {
    const float* X    = (const float*)d_in[0];
    const float* mask = (const float*)d_in[1];
    const float* Wq   = (const float*)d_in[2];
    const float* bq   = (const float*)d_in[3];
    const float* Wk   = (const float*)d_in[4];
    const float* bk   = (const float*)d_in[5];
    const float* Wv   = (const float*)d_in[6];
    const float* bv   = (const float*)d_in[7];
    const float* ew1  = (const float*)d_in[8];
    const float* eb1  = (const float*)d_in[9];
    const float* ew2  = (const float*)d_in[10];
    const float* eb2  = (const float*)d_in[11];
    const float* iw1  = (const float*)d_in[12];
    const float* ib1  = (const float*)d_in[13];
    const float* iw2  = (const float*)d_in[14];
    const float* ib2  = (const float*)d_in[15];
    float* out = (float*)d_out;

    u16* Xb  = (u16*)d_ws;
    u16* Wqb = Xb + (size_t)(BN * SN) * DN;
    u16* Wkb = Wqb + DN * DN;
    u16* Wvb = Wkb + DN * DN;
    u16* Qb  = Wvb + DN * DN;
    const size_t per = (size_t)BN * NHN * SN * DHN;
    u16* Kb2 = Qb + per;
    u16* Vb2 = Kb2 + per;   // V^T [B,NH,DH,S]

    dim3 gc(1536, 4);
    cvt_bf16<<<gc, 256, 0, stream>>>(X, Wq, Wk, Wv, Xb, Wqb, Wkb, Wvb);

    dim3 g1(36, 16);
    qkv_mfma<<<g1, 256, 0, stream>>>(Xb, Wqb, Wkb, Wvb, bq, bk, bv, Qb, Kb2, Vb2);

    dim3 g2(SN / 16, BN * NHN);            // (32, 48)
    attn_mfma<<<g2, 256, 0, stream>>>(Qb, Kb2, Vb2, mask,
                                      ew1, eb1, ew2, eb2,
                                      iw1, ib1, iw2, ib2, out);
}